// Round 3
// baseline (126.498 us; speedup 1.0000x reference)
//
#include <hip/hip_runtime.h>
#include <math.h>

#define OUTSZ   224
#define NBINS   8
#define NTH     256
#define IMG_H   512
#define IMG_W   512
#define HW      (IMG_H * IMG_W)   // 262144 = 2^18

// ---------------- pre-pass: (N,2,H,W) -> (N,H,W,2) ----------------
__global__ __launch_bounds__(NTH) void interleave_kernel(
    const float* __restrict__ flows, float2* __restrict__ inter)
{
    const int g   = blockIdx.x * NTH + threadIdx.x;  // one group = 4 pixels
    const int n   = g >> 16;                         // HW/4 = 65536 groups/plane
    const int hw4 = (g & 0xFFFF) << 2;
    const float4 a = *(const float4*)(flows + (size_t)(2 * n) * HW + hw4);
    const float4 b = *(const float4*)(flows + (size_t)(2 * n + 1) * HW + hw4);
    float4* o = (float4*)(inter + (size_t)n * HW + hw4);
    o[0] = make_float4(a.x, b.x, a.y, b.y);
    o[1] = make_float4(a.z, b.z, a.w, b.w);
}

// ---------------- main kernel ----------------
// IL=true : src is float2 (N,H,W,2) interleaved
// IL=false: src is float  (N,2,H,W) planar (fallback)
template <bool IL, int CHUNKS>
__global__ __launch_bounds__(NTH, 8) void velhist_kernel(
    const void* __restrict__ src,
    const float* __restrict__ boxes,   // (M,5)
    float* __restrict__ ws,            // partials if CHUNKS>1: [grid][16]
    float* __restrict__ out)           // (M,8) if CHUNKS==1
{
    constexpr int RPC   = OUTSZ / CHUNKS;
    constexpr int PXSH  = IL ? 3 : 2;        // bytes per pixel step
    constexpr int ROWSH = IL ? 12 : 11;      // bytes per image row
    constexpr int CHOFF = HW * 4;            // planar channel-1 byte offset

    const int bid   = blockIdx.x;
    const int m     = (CHUNKS == 1) ? bid : (bid / CHUNKS);
    const int chunk = (CHUNKS == 1) ? 0   : (bid - m * CHUNKS);
    const int tid   = threadIdx.x;

    __shared__ float2 s_h[NBINS * NTH];   // 16 KB  {sum, cnt}
    __shared__ float4 s_row[RPC];         // per-row y state

#pragma unroll
    for (int b = 0; b < NBINS; ++b)
        s_h[(b << 8) + tid] = make_float2(0.0f, 0.0f);

    const float bxf = boxes[m * 5 + 0];
    const float x1  = boxes[m * 5 + 1];
    const float y1  = boxes[m * 5 + 2];
    const float x2  = boxes[m * 5 + 3];
    const float y2  = boxes[m * 5 + 4];
    const int  bidx = (int)bxf;
    const float roi_w = fmaxf(x2 - x1, 1.0f);
    const float roi_h = fmaxf(y2 - y1, 1.0f);
    const float GINV  = 1.0f / (float)OUTSZ;

    // per-row y-state table (wave-uniform values, computed once per block)
    if (tid < RPC) {
        const int row   = chunk * RPC + tid;
        const float gy  = ((float)row + 0.5f) * GINV;
        const float py  = y1 + gy * roi_h;
        const bool  vy  = (py >= -1.0f) && (py <= (float)IMG_H);
        const float pcy = fminf(fmaxf(py, 0.0f), (float)(IMG_H - 1));
        const int   y0  = (int)pcy;
        const float fy  = pcy - (float)y0;
        const int   y1r = min(y0 + 1, IMG_H - 1);
        const float wy0 = vy ? (1.0f - fy) : 0.0f;
        const float wy1 = vy ? fy : -0.0f;           // sign bit encodes !vy
        s_row[tid] = make_float4(wy0, wy1,
                                 __int_as_float(y0  << ROWSH),
                                 __int_as_float(y1r << ROWSH));
    }

    // per-column x state (registers)
    const char* base;
    if (IL) base = (const char*)src + (size_t)bidx * HW * sizeof(float2);
    else    base = (const char*)src + (size_t)bidx * 2 * HW * sizeof(float);

    float wx0, wx1;
    int   x0b, x1b, vxi;
    {
        const float gx  = ((float)tid + 0.5f) * GINV;
        const float px  = x1 + gx * roi_w;
        const bool  vx  = (px >= -1.0f) && (px <= (float)IMG_W);
        const float pcx = fminf(fmaxf(px, 0.0f), (float)(IMG_W - 1));
        const int   x0  = (int)pcx;
        const float fx  = pcx - (float)x0;
        const int   x1i = min(x0 + 1, IMG_W - 1);
        const float vxf = vx ? 1.0f : 0.0f;
        x0b = x0  << PXSH;
        x1b = x1i << PXSH;
        wx0 = (1.0f - fx) * vxf;   // vx folded into weights
        wx1 = fx * vxf;
        vxi = vx ? 1 : 0;
    }

    __syncthreads();

    if (tid < OUTSZ) {
        float2* hptr = s_h + tid;   // hist slot: hptr[bin<<8]
#pragma unroll 4
        for (int r = 0; r < RPC; ++r) {
            const float4 rs = s_row[r];
            const int r0b = __float_as_int(rs.z);
            const int r1b = __float_as_int(rs.w);

            float a, b;
            if (IL) {
                const float2 p00 = *(const float2*)(base + (r0b + x0b));
                const float2 p01 = *(const float2*)(base + (r0b + x1b));
                const float2 p10 = *(const float2*)(base + (r1b + x0b));
                const float2 p11 = *(const float2*)(base + (r1b + x1b));
                const float w00 = rs.x * wx0, w01 = rs.x * wx1;
                const float w10 = rs.y * wx0, w11 = rs.y * wx1;
                a = p00.x * w00 + p01.x * w01 + p10.x * w10 + p11.x * w11;
                b = p00.y * w00 + p01.y * w01 + p10.y * w10 + p11.y * w11;
            } else {
                const float a00 = *(const float*)(base + (r0b + x0b));
                const float a01 = *(const float*)(base + (r0b + x1b));
                const float a10 = *(const float*)(base + (r1b + x0b));
                const float a11 = *(const float*)(base + (r1b + x1b));
                const float b00 = *(const float*)(base + CHOFF + (r0b + x0b));
                const float b01 = *(const float*)(base + CHOFF + (r0b + x1b));
                const float b10 = *(const float*)(base + CHOFF + (r1b + x0b));
                const float b11 = *(const float*)(base + CHOFF + (r1b + x1b));
                const float w00 = rs.x * wx0, w01 = rs.x * wx1;
                const float w10 = rs.y * wx0, w11 = rs.y * wx1;
                a = a00 * w00 + a01 * w01 + a10 * w10 + a11 * w11;
                b = b00 * w00 + b01 * w01 + b10 * w10 + b11 * w11;
            }

            const float mag = __builtin_amdgcn_sqrtf(a * a + b * b);

            // octant of atan2(a,b), Gray-decoded
            const int p = (a >= 0.0f);
            const int q = (b >= 0.0f);
            const int t = (fabsf(a) >= fabsf(b));
            const int u = p ^ q;
            int bin = (p << 2) | (u << 1) | (u ^ t);
            const int ok = vxi & (__float_as_int(rs.y) >= 0);  // vx && vy
            bin = ok ? bin : 4;                                // atan2(0,0)=0 -> bin 4

            float2 h = hptr[bin << 8];
            h.x += mag;
            h.y += 1.0f;
            hptr[bin << 8] = h;
        }
    }

    // tree-reduce 256 -> 1 per bin
    int sh = 7;
    for (int off = 128; off >= 1; off >>= 1, --sh) {
        __syncthreads();
        for (int w = tid; w < NBINS * off; w += NTH) {
            const int b = w >> sh;
            const int t2 = w & (off - 1);
            float2 lo = s_h[(b << 8) + t2];
            float2 hi = s_h[(b << 8) + t2 + off];
            lo.x += hi.x; lo.y += hi.y;
            s_h[(b << 8) + t2] = lo;
        }
    }
    __syncthreads();

    if (tid < NBINS) {
        const float2 h = s_h[tid << 8];
        if (CHUNKS == 1) {
            out[m * NBINS + tid] = (h.y != 0.0f) ? (h.x / fmaxf(h.y, 1.0f)) : 0.0f;
        } else {
            float* pp = ws + bid * 16;
            pp[tid]     = h.x;
            pp[tid + 8] = h.y;
        }
    }
}

__global__ __launch_bounds__(NTH) void finalize_kernel(
    const float* __restrict__ ws, float* __restrict__ out, int M, int chunks)
{
    const int i = blockIdx.x * NTH + threadIdx.x;
    if (i >= M * NBINS) return;
    const int m = i >> 3;
    const int b = i & 7;
    float s = 0.0f, c = 0.0f;
    for (int ch = 0; ch < chunks; ++ch) {
        const float* p = ws + (size_t)(m * chunks + ch) * 16;
        s += p[b];
        c += p[b + 8];
    }
    out[i] = (c != 0.0f) ? (s / fmaxf(c, 1.0f)) : 0.0f;
}

extern "C" void kernel_launch(void* const* d_in, const int* in_sizes, int n_in,
                              void* d_out, int out_size, void* d_ws, size_t ws_size,
                              hipStream_t stream) {
    const float* flows = (const float*)d_in[0];
    const float* boxes = (const float*)d_in[1];
    float* out = (float*)d_out;
    const int M = in_sizes[1] / 5;            // 512
    const int N = in_sizes[0] / (2 * HW);     // 8

    const int CH = 4;
    const size_t interBytes = (size_t)N * HW * sizeof(float2);      // 16.78 MB
    const size_t partBytes  = (size_t)M * CH * 16 * sizeof(float);  // 128 KB

    if (ws_size >= interBytes + partBytes) {
        float2* inter = (float2*)d_ws;
        float*  part  = (float*)((char*)d_ws + interBytes);
        interleave_kernel<<<dim3((N * HW / 4) / NTH), dim3(NTH), 0, stream>>>(flows, inter);
        velhist_kernel<true, 4><<<dim3(M * CH), dim3(NTH), 0, stream>>>(
            (const void*)inter, boxes, part, nullptr);
        finalize_kernel<<<dim3((M * NBINS + NTH - 1) / NTH), dim3(NTH), 0, stream>>>(
            part, out, M, CH);
    } else if (ws_size >= partBytes) {
        velhist_kernel<false, 4><<<dim3(M * CH), dim3(NTH), 0, stream>>>(
            (const void*)flows, boxes, (float*)d_ws, nullptr);
        finalize_kernel<<<dim3((M * NBINS + NTH - 1) / NTH), dim3(NTH), 0, stream>>>(
            (const float*)d_ws, out, M, CH);
    } else {
        velhist_kernel<false, 1><<<dim3(M), dim3(NTH), 0, stream>>>(
            (const void*)flows, boxes, nullptr, out);
    }
}